// Round 6
// baseline (239.667 us; speedup 1.0000x reference)
//
#include <hip/hip_runtime.h>
#include <hip/hip_bf16.h>
#include <math.h>

#define HID 256
#define CAP 128   // padded-CSR slots per node; max degree ~56 for E=320K,N=10K

typedef __attribute__((ext_vector_type(8))) short bf16x8;   // 8 bf16 = 4 VGPRs
typedef __attribute__((ext_vector_type(4))) float f32x4;

__device__ __forceinline__ float silu_f(float z) {
    return z / (1.0f + __expf(-z));
}
__device__ __forceinline__ unsigned short f2bf(float f) {   // round-to-nearest-even
    unsigned int u = __float_as_uint(f);
    u = (u + 0x7FFFu + ((u >> 16) & 1u)) >> 16;
    return (unsigned short)u;
}
__device__ __forceinline__ float bf2f(unsigned short b) {
    return __uint_as_float(((unsigned int)b) << 16);
}
__device__ __forceinline__ void max4(float4& m, ushort4 v) {
    m.x = fmaxf(m.x, bf2f(v.x));
    m.y = fmaxf(m.y, bf2f(v.y));
    m.z = fmaxf(m.z, bf2f(v.z));
    m.w = fmaxf(m.w, bf2f(v.w));
}

// ---- prep: fused [wcvt x4 | padded-CSR fill | goff+inv_cnt | zero d_out] ----
// blocks [0,1024): Wt[n][k] = bf16(W[k][n]) for 4 weight matrices
// blocks [1024, 1024+nh): csr[d*CAP + atomicAdd(cnt[d])] = src  (no scan needed)
// block  1024+nh: goff binary search (batch sorted) + inv_cnt
// blocks (1024+nh, 1024+nh+nz]: zero d_out
__global__ __launch_bounds__(256) void k_prep(
    const float* __restrict__ w0, const float* __restrict__ w1,
    const float* __restrict__ w2, const float* __restrict__ w3,
    unsigned short* __restrict__ o0, unsigned short* __restrict__ o1,
    unsigned short* __restrict__ o2, unsigned short* __restrict__ o3,
    const int* __restrict__ src, const int* __restrict__ dst,
    int* __restrict__ cnt, int* __restrict__ csr,
    const int* __restrict__ batch, float* __restrict__ inv_cnt,
    float* __restrict__ out, int out_elems,
    int N, int E, int G, int nh) {
    int b = blockIdx.x;
    int tid = threadIdx.x;
    if (b < 1024) {
        int i = b * 256 + tid;               // 0..262143
        int which = i >> 16;
        int j = i & 65535;
        int n = j >> 8, k = j & 255;
        const float* in = (which == 0) ? w0 : (which == 1) ? w1 : (which == 2) ? w2 : w3;
        unsigned short* op = (which == 0) ? o0 : (which == 1) ? o1 : (which == 2) ? o2 : o3;
        op[n * HID + k] = f2bf(in[k * HID + n]);
    } else if (b < 1024 + nh) {
        int e = (b - 1024) * 256 + tid;
        if (e < E) {
            int d = dst[e];
            int p = atomicAdd(&cnt[d], 1);
            if (p < CAP) csr[d * CAP + p] = src[e];
        }
    } else if (b == 1024 + nh) {
        __shared__ int sg[257];
        if (tid <= G) {
            int lo = 0, hi = N;
            while (lo < hi) {
                int mid = (lo + hi) >> 1;
                if (batch[mid] < tid) lo = mid + 1; else hi = mid;
            }
            sg[tid] = lo;
        }
        __syncthreads();
        if (tid < G) {
            int c = sg[tid + 1] - sg[tid];
            inv_cnt[tid] = 1.0f / (float)(c > 0 ? c : 1);
        }
    } else {
        int i = (b - 1024 - nh - 1) * 256 + tid;
        if (i < out_elems) out[i] = 0.0f;
    }
}

// ---- fused 2-layer MLP: t2 = (relu(A@Wa + ba))@Wb + bb, 32 rows/block ----
// FIRST: A = silu(x*Wemb + bemb) computed in-block (embed fused), bf16 copy -> hb.
// !FIRST: A read from global bf16 (hb).
// block = 32 rows, 4 waves; wave = 32 rows x 64 cols (2 row-subtiles x 4 n-tiles),
// B-fragment reused across the 2 row-subtiles. t1 passes through LDS (stride 264).
template <bool FIRST>
__global__ __launch_bounds__(256) void k_mlp(
    const float* __restrict__ x, const float* __restrict__ Wemb,
    const float* __restrict__ bemb, const unsigned short* __restrict__ Aglob,
    const unsigned short* __restrict__ Wta, const float* __restrict__ ba,
    const unsigned short* __restrict__ Wtb, const float* __restrict__ bbv,
    unsigned short* __restrict__ hb, unsigned short* __restrict__ t2, int M) {
    __shared__ unsigned short As[FIRST ? 32 : 1][264];
    __shared__ unsigned short t1s[32][264];
    int tid = threadIdx.x;
    int lane = tid & 63;
    int wave = tid >> 6;
    int quad = lane >> 4;
    int r = lane & 15;
    int m0 = blockIdx.x * 32;
    int colw = wave * 64;                     // wave's 64-col slice

    if (FIRST) {
        // embed: thread handles row = tid>>3, cols [c0, c0+32)
        int row = tid >> 3;
        int c0 = (tid & 7) * 32;
        int grow = m0 + row;
        float xv = (grow < M) ? x[grow] : 0.0f;
#pragma unroll
        for (int j = 0; j < 8; ++j) {
            int c = c0 + j * 4;
            ushort4 q;
            q.x = f2bf(silu_f(xv * Wemb[c + 0] + bemb[c + 0]));
            q.y = f2bf(silu_f(xv * Wemb[c + 1] + bemb[c + 1]));
            q.z = f2bf(silu_f(xv * Wemb[c + 2] + bemb[c + 2]));
            q.w = f2bf(silu_f(xv * Wemb[c + 3] + bemb[c + 3]));
            if (grow < M) *(ushort4*)(hb + (size_t)grow * HID + c) = q;
            *(ushort4*)&As[row][c] = q;
        }
        __syncthreads();
    }

    // ---- GEMM1: acc[rt][nt] over 2 row-subtiles x 4 n-tiles ----
    f32x4 acc[2][4];
#pragma unroll
    for (int rt = 0; rt < 2; ++rt)
#pragma unroll
        for (int nt = 0; nt < 4; ++nt) acc[rt][nt] = (f32x4)0.0f;

    int ar0 = m0 + r;        if (ar0 >= M) ar0 = M - 1;   // clamped, never stored
    int ar1 = m0 + 16 + r;   if (ar1 >= M) ar1 = M - 1;

#pragma unroll
    for (int ks = 0; ks < 8; ++ks) {
        bf16x8 a0, a1;
        if (FIRST) {
            a0 = *(const bf16x8*)&As[r][ks * 32 + quad * 8];
            a1 = *(const bf16x8*)&As[(FIRST ? r + 16 : 0)][ks * 32 + quad * 8];
        } else {
            a0 = *(const bf16x8*)(Aglob + (size_t)ar0 * HID + ks * 32 + quad * 8);
            a1 = *(const bf16x8*)(Aglob + (size_t)ar1 * HID + ks * 32 + quad * 8);
        }
#pragma unroll
        for (int nt = 0; nt < 4; ++nt) {
            bf16x8 bfr = *(const bf16x8*)(Wta + (size_t)(colw + nt * 16 + r) * HID
                                          + ks * 32 + quad * 8);
            acc[0][nt] = __builtin_amdgcn_mfma_f32_16x16x32_bf16(a0, bfr, acc[0][nt], 0, 0, 0);
            acc[1][nt] = __builtin_amdgcn_mfma_f32_16x16x32_bf16(a1, bfr, acc[1][nt], 0, 0, 0);
        }
    }

    // t1 = bf16(relu(acc + ba)) -> LDS  (C/D: col=r, row=quad*4+i within tile)
#pragma unroll
    for (int nt = 0; nt < 4; ++nt) {
        int col = colw + nt * 16 + r;
        float bv = ba[col];
#pragma unroll
        for (int rt = 0; rt < 2; ++rt)
#pragma unroll
            for (int i = 0; i < 4; ++i) {
                float v = fmaxf(acc[rt][nt][i] + bv, 0.0f);
                t1s[rt * 16 + quad * 4 + i][col] = f2bf(v);
            }
    }
    __syncthreads();

    // ---- GEMM2 ----
    f32x4 acc2[2][4];
#pragma unroll
    for (int rt = 0; rt < 2; ++rt)
#pragma unroll
        for (int nt = 0; nt < 4; ++nt) acc2[rt][nt] = (f32x4)0.0f;
#pragma unroll
    for (int ks = 0; ks < 8; ++ks) {
        bf16x8 a0 = *(const bf16x8*)&t1s[r][ks * 32 + quad * 8];
        bf16x8 a1 = *(const bf16x8*)&t1s[r + 16][ks * 32 + quad * 8];
#pragma unroll
        for (int nt = 0; nt < 4; ++nt) {
            bf16x8 bfr = *(const bf16x8*)(Wtb + (size_t)(colw + nt * 16 + r) * HID
                                          + ks * 32 + quad * 8);
            acc2[0][nt] = __builtin_amdgcn_mfma_f32_16x16x32_bf16(a0, bfr, acc2[0][nt], 0, 0, 0);
            acc2[1][nt] = __builtin_amdgcn_mfma_f32_16x16x32_bf16(a1, bfr, acc2[1][nt], 0, 0, 0);
        }
    }

    // epilogue: t2 = bf16(acc2 + bb)
#pragma unroll
    for (int nt = 0; nt < 4; ++nt) {
        int col = colw + nt * 16 + r;
        float bv = bbv[col];
#pragma unroll
        for (int rt = 0; rt < 2; ++rt)
#pragma unroll
            for (int i = 0; i < 4; ++i) {
                int row = m0 + rt * 16 + quad * 4 + i;
                if (row < M) t2[(size_t)row * HID + col] = f2bf(acc2[rt][nt][i] + bv);
            }
    }
}

// ---- scatter-max + silu + residual (bf16), 4 waves/node, 8x unrolled gather ----
// LAST: instead of storing hb, fuse global mean pool: atomicAdd(out, hv * inv_cnt[g]).
template <bool LAST>
__global__ __launch_bounds__(256) void k_agg(const unsigned short* __restrict__ t2,
                                             const int* __restrict__ cnt,
                                             const int* __restrict__ csr,
                                             unsigned short* __restrict__ hb,
                                             const int* __restrict__ batch,
                                             const float* __restrict__ inv_cnt,
                                             float* __restrict__ out, int N) {
    __shared__ float4 red[4][64];
    int node = blockIdx.x;
    int wave = threadIdx.x >> 6;
    int lane = threadIdx.x & 63;
    int deg = cnt[node];
    if (deg > CAP) deg = CAP;
    const int* rowp = csr + (size_t)node * CAP;

    float4 m = make_float4(-INFINITY, -INFINITY, -INFINITY, -INFINITY);
    int per = (deg + 3) >> 2;
    int lo = wave * per;
    int hi = lo + per; if (hi > deg) hi = deg;
    const unsigned short* base = t2 + lane * 4;
    int i = lo;
    for (; i + 8 <= hi; i += 8) {
        int s[8];
#pragma unroll
        for (int j = 0; j < 8; ++j) s[j] = rowp[i + j];
        ushort4 v[8];
#pragma unroll
        for (int j = 0; j < 8; ++j) v[j] = *(const ushort4*)(base + (size_t)s[j] * HID);
#pragma unroll
        for (int j = 0; j < 8; ++j) max4(m, v[j]);
    }
    if (i + 4 <= hi) {
        int s[4];
#pragma unroll
        for (int j = 0; j < 4; ++j) s[j] = rowp[i + j];
        ushort4 v[4];
#pragma unroll
        for (int j = 0; j < 4; ++j) v[j] = *(const ushort4*)(base + (size_t)s[j] * HID);
#pragma unroll
        for (int j = 0; j < 4; ++j) max4(m, v[j]);
        i += 4;
    }
    for (; i < hi; ++i) {
        int s = rowp[i];
        ushort4 v = *(const ushort4*)(base + (size_t)s * HID);
        max4(m, v);
    }
    red[wave][lane] = m;
    __syncthreads();
    if (wave == 0) {
        float4 m1 = red[1][lane], m2 = red[2][lane], m3 = red[3][lane];
        m.x = fmaxf(fmaxf(m.x, m1.x), fmaxf(m2.x, m3.x));
        m.y = fmaxf(fmaxf(m.y, m1.y), fmaxf(m2.y, m3.y));
        m.z = fmaxf(fmaxf(m.z, m1.z), fmaxf(m2.z, m3.z));
        m.w = fmaxf(fmaxf(m.w, m1.w), fmaxf(m2.w, m3.w));
        if (deg == 0) m = make_float4(0.f, 0.f, 0.f, 0.f);   // isneginf -> 0

        size_t o = (size_t)node * HID + lane * 4;
        ushort4 hq = *(const ushort4*)(hb + o);
        float4 hv;
        hv.x = bf2f(hq.x) + silu_f(m.x);
        hv.y = bf2f(hq.y) + silu_f(m.y);
        hv.z = bf2f(hq.z) + silu_f(m.z);
        hv.w = bf2f(hq.w) + silu_f(m.w);
        if (LAST) {
            int g = batch[node];
            float ic = inv_cnt[g];
            float* op = out + (size_t)g * HID + lane * 4;
            atomicAdd(op + 0, hv.x * ic);
            atomicAdd(op + 1, hv.y * ic);
            atomicAdd(op + 2, hv.z * ic);
            atomicAdd(op + 3, hv.w * ic);
        } else {
            ushort4 q;
            q.x = f2bf(hv.x); q.y = f2bf(hv.y); q.z = f2bf(hv.z); q.w = f2bf(hv.w);
            *(ushort4*)(hb + o) = q;
        }
    }
}

extern "C" void kernel_launch(void* const* d_in, const int* in_sizes, int n_in,
                              void* d_out, int out_size, void* d_ws, size_t ws_size,
                              hipStream_t stream) {
    const float* x     = (const float*)d_in[0];
    const int*   ei    = (const int*)d_in[1];
    const int*   batch = (const int*)d_in[2];
    const float* Wemb  = (const float*)d_in[3];
    const float* bemb  = (const float*)d_in[4];
    const float* W1a   = (const float*)d_in[5];
    const float* b1a   = (const float*)d_in[6];
    const float* W1b   = (const float*)d_in[7];
    const float* b1b   = (const float*)d_in[8];
    const float* W2a   = (const float*)d_in[9];
    const float* b2a   = (const float*)d_in[10];
    const float* W2b   = (const float*)d_in[11];
    const float* b2b   = (const float*)d_in[12];
    float* out = (float*)d_out;

    const int N = in_sizes[0];          // 10000
    const int E = in_sizes[1] / 2;      // 320000
    const int G = out_size / HID;       // 64
    const int* src = ei;
    const int* dst = ei + E;

    char* ws = (char*)d_ws;
    unsigned short* hb   = (unsigned short*)ws; ws += (size_t)N * HID * 2;
    unsigned short* t2   = (unsigned short*)ws; ws += (size_t)N * HID * 2;
    unsigned short* Wt1a = (unsigned short*)ws; ws += (size_t)HID * HID * 2;
    unsigned short* Wt1b = (unsigned short*)ws; ws += (size_t)HID * HID * 2;
    unsigned short* Wt2a = (unsigned short*)ws; ws += (size_t)HID * HID * 2;
    unsigned short* Wt2b = (unsigned short*)ws; ws += (size_t)HID * HID * 2;
    int*   cnt     = (int*)ws;   ws += (size_t)N * 4;
    float* inv_cnt = (float*)ws; ws += (size_t)G * 4;
    int*   csr     = (int*)ws;   ws += (size_t)N * CAP * 4;

    const int nh = (E + 255) / 256;
    const int nz = (out_size + 255) / 256;

    // 1. zero per-node counters (40 KB)
    hipMemsetAsync(cnt, 0, (size_t)N * 4, stream);

    // 2. fused prep: weight cvt | padded-CSR fill | goff+inv_cnt | zero d_out
    k_prep<<<1024 + nh + 1 + nz, 256, 0, stream>>>(W1a, W1b, W2a, W2b,
                                                   Wt1a, Wt1b, Wt2a, Wt2b,
                                                   src, dst, cnt, csr,
                                                   batch, inv_cnt, out, out_size,
                                                   N, E, G, nh);

    dim3 mgrid((N + 31) / 32);

    // 3-4. conv1: fused [embed + mlp], then scatter-max (+silu+residual in bf16)
    k_mlp<true ><<<mgrid, 256, 0, stream>>>(x, Wemb, bemb, nullptr,
                                            Wt1a, b1a, Wt1b, b1b, hb, t2, N);
    k_agg<false><<<N, 256, 0, stream>>>(t2, cnt, csr, hb, batch, inv_cnt, out, N);

    // 5-6. conv2: fused mlp (A = hb), then scatter-max + fused mean-pool
    k_mlp<false><<<mgrid, 256, 0, stream>>>(nullptr, nullptr, nullptr, hb,
                                            Wt2a, b2a, Wt2b, b2b, hb, t2, N);
    k_agg<true ><<<N, 256, 0, stream>>>(t2, cnt, csr, hb, batch, inv_cnt, out, N);
}

// Round 7
// 210.758 us; speedup vs baseline: 1.1372x; 1.1372x over previous
//
#include <hip/hip_runtime.h>
#include <hip/hip_bf16.h>
#include <math.h>

#define HID 256
#define CAP 128   // padded-CSR slots per node; max degree ~56 for E=320K,N=10K

typedef __attribute__((ext_vector_type(8))) short bf16x8;   // 8 bf16 = 4 VGPRs
typedef __attribute__((ext_vector_type(4))) float f32x4;

__device__ __forceinline__ float silu_f(float z) {
    return z / (1.0f + __expf(-z));
}
__device__ __forceinline__ unsigned short f2bf(float f) {   // round-to-nearest-even
    unsigned int u = __float_as_uint(f);
    u = (u + 0x7FFFu + ((u >> 16) & 1u)) >> 16;
    return (unsigned short)u;
}
__device__ __forceinline__ float bf2f(unsigned short b) {
    return __uint_as_float(((unsigned int)b) << 16);
}
__device__ __forceinline__ void max4(float4& m, ushort4 v) {
    m.x = fmaxf(m.x, bf2f(v.x));
    m.y = fmaxf(m.y, bf2f(v.y));
    m.z = fmaxf(m.z, bf2f(v.z));
    m.w = fmaxf(m.w, bf2f(v.w));
}

// ---- prep: fused [wcvt x4 | padded-CSR fill | graph offsets] via block ranges ----
__global__ __launch_bounds__(256) void k_prep(
    const float* __restrict__ w0, const float* __restrict__ w1,
    const float* __restrict__ w2, const float* __restrict__ w3,
    unsigned short* __restrict__ o0, unsigned short* __restrict__ o1,
    unsigned short* __restrict__ o2, unsigned short* __restrict__ o3,
    const int* __restrict__ src, const int* __restrict__ dst,
    int* __restrict__ cnt, int* __restrict__ csr,
    const int* __restrict__ batch, int* __restrict__ goff,
    int N, int E, int G, int nh) {
    int b = blockIdx.x;
    int tid = threadIdx.x;
    if (b < 1024) {
        int i = b * 256 + tid;               // 0..262143
        int which = i >> 16;
        int j = i & 65535;
        int n = j >> 8, k = j & 255;
        const float* in = (which == 0) ? w0 : (which == 1) ? w1 : (which == 2) ? w2 : w3;
        unsigned short* op = (which == 0) ? o0 : (which == 1) ? o1 : (which == 2) ? o2 : o3;
        op[n * HID + k] = f2bf(in[k * HID + n]);
    } else if (b < 1024 + nh) {
        int e = (b - 1024) * 256 + tid;
        if (e < E) {
            int d = dst[e];
            int p = atomicAdd(&cnt[d], 1);
            if (p < CAP) csr[d * CAP + p] = src[e];
        }
    } else {
        int g = tid;
        if (g > G) return;
        int lo = 0, hi = N;
        while (lo < hi) {
            int mid = (lo + hi) >> 1;
            if (batch[mid] < g) lo = mid + 1; else hi = mid;
        }
        goff[g] = lo;
    }
}

// ---- fused 2-layer MLP: t2 = (relu(A@Wa + ba))@Wb + bb, 32 rows/block ----
// FIRST: A = silu(x*Wemb + bemb) computed in-block (embed fused), bf16 copy -> hb.
// !FIRST: A read from global bf16 (hb).
template <bool FIRST>
__global__ __launch_bounds__(256) void k_mlp(
    const float* __restrict__ x, const float* __restrict__ Wemb,
    const float* __restrict__ bemb, const unsigned short* __restrict__ Aglob,
    const unsigned short* __restrict__ Wta, const float* __restrict__ ba,
    const unsigned short* __restrict__ Wtb, const float* __restrict__ bbv,
    unsigned short* __restrict__ hb, unsigned short* __restrict__ t2, int M) {
    __shared__ unsigned short As[FIRST ? 32 : 1][264];
    __shared__ unsigned short t1s[32][264];
    int tid = threadIdx.x;
    int lane = tid & 63;
    int wave = tid >> 6;
    int quad = lane >> 4;
    int r = lane & 15;
    int m0 = blockIdx.x * 32;
    int colw = wave * 64;                     // wave's 64-col slice

    if (FIRST) {
        int row = tid >> 3;
        int c0 = (tid & 7) * 32;
        int grow = m0 + row;
        float xv = (grow < M) ? x[grow] : 0.0f;
#pragma unroll
        for (int j = 0; j < 8; ++j) {
            int c = c0 + j * 4;
            ushort4 q;
            q.x = f2bf(silu_f(xv * Wemb[c + 0] + bemb[c + 0]));
            q.y = f2bf(silu_f(xv * Wemb[c + 1] + bemb[c + 1]));
            q.z = f2bf(silu_f(xv * Wemb[c + 2] + bemb[c + 2]));
            q.w = f2bf(silu_f(xv * Wemb[c + 3] + bemb[c + 3]));
            if (grow < M) *(ushort4*)(hb + (size_t)grow * HID + c) = q;
            *(ushort4*)&As[row][c] = q;
        }
        __syncthreads();
    }

    // ---- GEMM1 ----
    f32x4 acc[2][4];
#pragma unroll
    for (int rt = 0; rt < 2; ++rt)
#pragma unroll
        for (int nt = 0; nt < 4; ++nt) acc[rt][nt] = (f32x4)0.0f;

    int ar0 = m0 + r;        if (ar0 >= M) ar0 = M - 1;   // clamped, never stored
    int ar1 = m0 + 16 + r;   if (ar1 >= M) ar1 = M - 1;

#pragma unroll
    for (int ks = 0; ks < 8; ++ks) {
        bf16x8 a0, a1;
        if (FIRST) {
            a0 = *(const bf16x8*)&As[r][ks * 32 + quad * 8];
            a1 = *(const bf16x8*)&As[(FIRST ? r + 16 : 0)][ks * 32 + quad * 8];
        } else {
            a0 = *(const bf16x8*)(Aglob + (size_t)ar0 * HID + ks * 32 + quad * 8);
            a1 = *(const bf16x8*)(Aglob + (size_t)ar1 * HID + ks * 32 + quad * 8);
        }
#pragma unroll
        for (int nt = 0; nt < 4; ++nt) {
            bf16x8 bfr = *(const bf16x8*)(Wta + (size_t)(colw + nt * 16 + r) * HID
                                          + ks * 32 + quad * 8);
            acc[0][nt] = __builtin_amdgcn_mfma_f32_16x16x32_bf16(a0, bfr, acc[0][nt], 0, 0, 0);
            acc[1][nt] = __builtin_amdgcn_mfma_f32_16x16x32_bf16(a1, bfr, acc[1][nt], 0, 0, 0);
        }
    }

    // t1 = bf16(relu(acc + ba)) -> LDS
#pragma unroll
    for (int nt = 0; nt < 4; ++nt) {
        int col = colw + nt * 16 + r;
        float bv = ba[col];
#pragma unroll
        for (int rt = 0; rt < 2; ++rt)
#pragma unroll
            for (int i = 0; i < 4; ++i) {
                float v = fmaxf(acc[rt][nt][i] + bv, 0.0f);
                t1s[rt * 16 + quad * 4 + i][col] = f2bf(v);
            }
    }
    __syncthreads();

    // ---- GEMM2 ----
    f32x4 acc2[2][4];
#pragma unroll
    for (int rt = 0; rt < 2; ++rt)
#pragma unroll
        for (int nt = 0; nt < 4; ++nt) acc2[rt][nt] = (f32x4)0.0f;
#pragma unroll
    for (int ks = 0; ks < 8; ++ks) {
        bf16x8 a0 = *(const bf16x8*)&t1s[r][ks * 32 + quad * 8];
        bf16x8 a1 = *(const bf16x8*)&t1s[r + 16][ks * 32 + quad * 8];
#pragma unroll
        for (int nt = 0; nt < 4; ++nt) {
            bf16x8 bfr = *(const bf16x8*)(Wtb + (size_t)(colw + nt * 16 + r) * HID
                                          + ks * 32 + quad * 8);
            acc2[0][nt] = __builtin_amdgcn_mfma_f32_16x16x32_bf16(a0, bfr, acc2[0][nt], 0, 0, 0);
            acc2[1][nt] = __builtin_amdgcn_mfma_f32_16x16x32_bf16(a1, bfr, acc2[1][nt], 0, 0, 0);
        }
    }

    // epilogue: t2 = bf16(acc2 + bb)
#pragma unroll
    for (int nt = 0; nt < 4; ++nt) {
        int col = colw + nt * 16 + r;
        float bv = bbv[col];
#pragma unroll
        for (int rt = 0; rt < 2; ++rt)
#pragma unroll
            for (int i = 0; i < 4; ++i) {
                int row = m0 + rt * 16 + quad * 4 + i;
                if (row < M) t2[(size_t)row * HID + col] = f2bf(acc2[rt][nt][i] + bv);
            }
    }
}

// ---- scatter-max + silu + residual: wave-autonomous, grid-stride over nodes ----
// Each WAVE owns whole nodes (no cross-wave split, no LDS, no syncthreads).
// 8-deep gather pipeline; hb row prefetched before the gather loop.
__global__ __launch_bounds__(256) void k_agg(const unsigned short* __restrict__ t2,
                                             const int* __restrict__ cnt,
                                             const int* __restrict__ csr,
                                             unsigned short* __restrict__ hb,
                                             int N, int total_waves) {
    int lane = threadIdx.x & 63;
    int gwave = (blockIdx.x * blockDim.x + threadIdx.x) >> 6;
    const unsigned short* base = t2 + lane * 4;

    for (int node = gwave; node < N; node += total_waves) {
        int deg = cnt[node];
        if (deg > CAP) deg = CAP;
        const int* rowp = csr + (size_t)node * CAP;
        size_t o = (size_t)node * HID + lane * 4;
        ushort4 hq = *(const ushort4*)(hb + o);          // prefetch residual row

        float4 m = make_float4(-INFINITY, -INFINITY, -INFINITY, -INFINITY);
        int i = 0;
        for (; i + 8 <= deg; i += 8) {
            int s[8];
#pragma unroll
            for (int j = 0; j < 8; ++j) s[j] = rowp[i + j];
            ushort4 v[8];
#pragma unroll
            for (int j = 0; j < 8; ++j) v[j] = *(const ushort4*)(base + (size_t)s[j] * HID);
#pragma unroll
            for (int j = 0; j < 8; ++j) max4(m, v[j]);
        }
        if (i + 4 <= deg) {
            int s[4];
#pragma unroll
            for (int j = 0; j < 4; ++j) s[j] = rowp[i + j];
            ushort4 v[4];
#pragma unroll
            for (int j = 0; j < 4; ++j) v[j] = *(const ushort4*)(base + (size_t)s[j] * HID);
#pragma unroll
            for (int j = 0; j < 4; ++j) max4(m, v[j]);
            i += 4;
        }
        for (; i < deg; ++i) {
            int s = rowp[i];
            ushort4 v = *(const ushort4*)(base + (size_t)s * HID);
            max4(m, v);
        }
        if (deg == 0) m = make_float4(0.f, 0.f, 0.f, 0.f);   // isneginf -> 0

        ushort4 q;
        q.x = f2bf(bf2f(hq.x) + silu_f(m.x));
        q.y = f2bf(bf2f(hq.y) + silu_f(m.y));
        q.z = f2bf(bf2f(hq.z) + silu_f(m.z));
        q.w = f2bf(bf2f(hq.w) + silu_f(m.w));
        *(ushort4*)(hb + o) = q;
    }
}

// ---- mean pool per graph (bf16 input): 1024 threads, 4 row-chunks ----
__global__ __launch_bounds__(1024) void k_pool(const unsigned short* __restrict__ hb,
                                               const int* __restrict__ goff,
                                               float* __restrict__ out) {
    __shared__ float part[3][HID];
    int g = blockIdx.x;
    int tid = threadIdx.x;
    int c = tid & 255;
    int chunk = tid >> 8;
    int beg = goff[g], end = goff[g + 1];
    float s = 0.f;
    for (int n = beg + chunk; n < end; n += 4) s += bf2f(hb[(size_t)n * HID + c]);
    if (chunk > 0) part[chunk - 1][c] = s;
    __syncthreads();
    if (chunk == 0) {
        s += part[0][c] + part[1][c] + part[2][c];
        int cnt = end - beg;
        out[g * HID + c] = s / (float)(cnt > 0 ? cnt : 1);
    }
}

extern "C" void kernel_launch(void* const* d_in, const int* in_sizes, int n_in,
                              void* d_out, int out_size, void* d_ws, size_t ws_size,
                              hipStream_t stream) {
    const float* x     = (const float*)d_in[0];
    const int*   ei    = (const int*)d_in[1];
    const int*   batch = (const int*)d_in[2];
    const float* Wemb  = (const float*)d_in[3];
    const float* bemb  = (const float*)d_in[4];
    const float* W1a   = (const float*)d_in[5];
    const float* b1a   = (const float*)d_in[6];
    const float* W1b   = (const float*)d_in[7];
    const float* b1b   = (const float*)d_in[8];
    const float* W2a   = (const float*)d_in[9];
    const float* b2a   = (const float*)d_in[10];
    const float* W2b   = (const float*)d_in[11];
    const float* b2b   = (const float*)d_in[12];
    float* out = (float*)d_out;

    const int N = in_sizes[0];          // 10000
    const int E = in_sizes[1] / 2;      // 320000
    const int G = out_size / HID;       // 64
    const int* src = ei;
    const int* dst = ei + E;

    char* ws = (char*)d_ws;
    unsigned short* hb   = (unsigned short*)ws; ws += (size_t)N * HID * 2;
    unsigned short* t2   = (unsigned short*)ws; ws += (size_t)N * HID * 2;
    unsigned short* Wt1a = (unsigned short*)ws; ws += (size_t)HID * HID * 2;
    unsigned short* Wt1b = (unsigned short*)ws; ws += (size_t)HID * HID * 2;
    unsigned short* Wt2a = (unsigned short*)ws; ws += (size_t)HID * HID * 2;
    unsigned short* Wt2b = (unsigned short*)ws; ws += (size_t)HID * HID * 2;
    int* cnt  = (int*)ws; ws += (size_t)N * 4;
    int* goff = (int*)ws; ws += (size_t)(G + 1) * 4;
    int* csr  = (int*)ws; ws += (size_t)N * CAP * 4;

    const int nh = (E + 255) / 256;

    // 1. zero per-node counters (40 KB)
    hipMemsetAsync(cnt, 0, (size_t)N * 4, stream);

    // 2. fused prep: weight cvt | padded-CSR fill | graph offsets
    k_prep<<<1024 + nh + 1, 256, 0, stream>>>(W1a, W1b, W2a, W2b,
                                              Wt1a, Wt1b, Wt2a, Wt2b,
                                              src, dst, cnt, csr,
                                              batch, goff, N, E, G, nh);

    dim3 mgrid((N + 31) / 32);
    const int agg_blocks = 1250;                       // 5000 waves, ~2 nodes/wave
    const int total_waves = agg_blocks * 4;

    // 3-4. conv1: fused [embed + mlp], then wave-autonomous scatter-max
    k_mlp<true ><<<mgrid, 256, 0, stream>>>(x, Wemb, bemb, nullptr,
                                            Wt1a, b1a, Wt1b, b1b, hb, t2, N);
    k_agg<<<agg_blocks, 256, 0, stream>>>(t2, cnt, csr, hb, N, total_waves);

    // 5-6. conv2
    k_mlp<false><<<mgrid, 256, 0, stream>>>(nullptr, nullptr, nullptr, hb,
                                            Wt2a, b2a, Wt2b, b2b, hb, t2, N);
    k_agg<<<agg_blocks, 256, 0, stream>>>(t2, cnt, csr, hb, N, total_waves);

    // 7. global mean pool (bf16 hb -> fp32 out)
    k_pool<<<G, 1024, 0, stream>>>(hb, goff, out);
}